// Round 2
// baseline (188.601 us; speedup 1.0000x reference)
//
#include <hip/hip_runtime.h>
#include <hip/hip_bf16.h>
#include <cstdint>
#include <cmath>

// Problem constants
#define T_SEQ 16384
#define DMODEL 512        // D_IN = D_HID = D_OUT = 512
#define NCHUNK 256        // scan chunks
#define LCHUNK 64         // T_SEQ / NCHUNK
#define XS_N   (T_SEQ * DMODEL)     // 8388608
#define W_N    (DMODEL * DMODEL)    // 262144

typedef __bf16 bf16x8 __attribute__((ext_vector_type(8)));
typedef float  f32x4  __attribute__((ext_vector_type(4)));

using bf16 = __hip_bfloat16;

__device__ __forceinline__ void load_lds16(const void* g, void* l) {
    __builtin_amdgcn_global_load_lds((const __attribute__((address_space(1))) void*)g,
                                     (__attribute__((address_space(3))) void*)l,
                                     16, 0, 0);
}

// ---------------------------------------------------------------------------
// Kernel 0: dtype detector. If xs is fp32, its 16-bit words include random
// mantissa halves -> reinterpreted-as-bf16 values with huge exponents / NaN.
// If xs is bf16 N(0,1), all 2048 samples are sane (|v| < 16).
// flag = 1 -> inputs are fp32 ; flag = 0 -> inputs are bf16.
// ---------------------------------------------------------------------------
__global__ void k_detect(const unsigned short* __restrict__ raw, int* __restrict__ flag)
{
    __shared__ int s_bad;
    const int t = threadIdx.x;
    if (t == 0) s_bad = 0;
    __syncthreads();
    int bad = 0;
    for (int i = t; i < 2048; i += 256) {
        const unsigned short u = raw[i];
        const int e = (u >> 7) & 0xFF;   // bf16 exponent field
        if (e >= 141) bad = 1;           // |v| >= 16384, or Inf/NaN
    }
    if (bad) atomicOr(&s_bad, 1);
    __syncthreads();
    if (t == 0) *flag = s_bad;
}

// ---------------------------------------------------------------------------
// Conversion to canonical bf16 (matrices) / fp32 (biases)
// ---------------------------------------------------------------------------
__global__ void k_convert_bf16(const void* __restrict__ src, bf16* __restrict__ dst,
                               int n, const int* __restrict__ flag)
{
    const int i = blockIdx.x * 256 + threadIdx.x;
    if (i < n) {
        if (*flag) dst[i] = __float2bfloat16(((const float*)src)[i]);
        else       dst[i] = ((const bf16*)src)[i];
    }
}

__global__ void k_convert_bias(const void* __restrict__ s0, const void* __restrict__ s1,
                               const void* __restrict__ s2,
                               float* __restrict__ d0, float* __restrict__ d1,
                               float* __restrict__ d2, const int* __restrict__ flag)
{
    const int i = blockIdx.x * 256 + threadIdx.x;
    if (i < DMODEL) {
        if (*flag) {
            d0[i] = ((const float*)s0)[i];
            d1[i] = ((const float*)s1)[i];
            d2[i] = ((const float*)s2)[i];
        } else {
            d0[i] = __bfloat162float(((const bf16*)s0)[i]);
            d1[i] = __bfloat162float(((const bf16*)s1)[i]);
            d2[i] = __bfloat162float(((const bf16*)s2)[i]);
        }
    }
}

// ---------------------------------------------------------------------------
// Kernel 1: fused dual GEMM  zpre = xs@Wz^T, hpre = xs@Wh^T  (NT layout)
// epilogue: z = sigmoid(zpre+bz); a = 1-z; b = z*(hpre+bh)  -> fp32 ws
// tile 128x128, BK=64, 256 threads (2x2 waves, each 64x64 = 4x4 mfma tiles)
// ---------------------------------------------------------------------------
__global__ __launch_bounds__(256, 2) void gemm_zh(
    const bf16* __restrict__ xs, const bf16* __restrict__ Wz, const float* __restrict__ bz,
    const bf16* __restrict__ Wh, const float* __restrict__ bh,
    float* __restrict__ a_ws, float* __restrict__ b_ws)
{
    __shared__ __bf16 As[128 * 64];
    __shared__ __bf16 Zs[128 * 64];
    __shared__ __bf16 Hs[128 * 64];

    const int tid  = threadIdx.x;
    const int bn   = blockIdx.x;   // 0..3   (N tile)
    const int bm   = blockIdx.y;   // 0..127 (M tile)
    const int lane = tid & 63;
    const int wave = tid >> 6;
    const int wm   = wave >> 1;    // 0..1
    const int wn   = wave & 1;     // 0..1

    f32x4 accz[4][4], acch[4][4];
    #pragma unroll
    for (int i = 0; i < 4; ++i)
        #pragma unroll
        for (int j = 0; j < 4; ++j) {
            accz[i][j] = (f32x4){0.f, 0.f, 0.f, 0.f};
            acch[i][j] = (f32x4){0.f, 0.f, 0.f, 0.f};
        }

    // staging: tile is 128 rows x 64 cols bf16 = 16 KB = 1024 chunks of 16B
    const int row0 = tid >> 3;       // +32 per it
    const int k8   = tid & 7;

    const bf16* xg = xs + (size_t)(bm * 128) * DMODEL + k8 * 8;
    const bf16* zg = Wz + (size_t)(bn * 128) * DMODEL + k8 * 8;
    const bf16* hg = Wh + (size_t)(bn * 128) * DMODEL + k8 * 8;

    const int quad = lane >> 4;
    const int col  = lane & 15;

    for (int k0 = 0; k0 < DMODEL; k0 += 64) {
        #pragma unroll
        for (int it = 0; it < 4; ++it) {
            const int row   = row0 + it * 32;
            const int chunk = it * 256 + tid;
            load_lds16(xg + (size_t)row * DMODEL + k0, &As[chunk * 8]);
            load_lds16(zg + (size_t)row * DMODEL + k0, &Zs[chunk * 8]);
            load_lds16(hg + (size_t)row * DMODEL + k0, &Hs[chunk * 8]);
        }
        __syncthreads();

        #pragma unroll
        for (int kk = 0; kk < 2; ++kk) {
            const int kb = kk * 32 + quad * 8;
            bf16x8 af[4], zf[4], hf[4];
            #pragma unroll
            for (int i = 0; i < 4; ++i) {
                const int am  = wm * 64 + i * 16 + col;
                const int bnr = wn * 64 + i * 16 + col;
                af[i] = *(const bf16x8*)&As[am * 64 + kb];
                zf[i] = *(const bf16x8*)&Zs[bnr * 64 + kb];
                hf[i] = *(const bf16x8*)&Hs[bnr * 64 + kb];
            }
            #pragma unroll
            for (int i = 0; i < 4; ++i)
                #pragma unroll
                for (int j = 0; j < 4; ++j) {
                    accz[i][j] = __builtin_amdgcn_mfma_f32_16x16x32_bf16(af[i], zf[j], accz[i][j], 0, 0, 0);
                    acch[i][j] = __builtin_amdgcn_mfma_f32_16x16x32_bf16(af[i], hf[j], acch[i][j], 0, 0, 0);
                }
        }
        __syncthreads();
    }

    // epilogue: D layout col=lane&15 (n), row=quad*4+reg (m)
    #pragma unroll
    for (int j = 0; j < 4; ++j) {
        const int n = bn * 128 + wn * 64 + j * 16 + col;
        const float bzv = bz[n];
        const float bhv = bh[n];
        #pragma unroll
        for (int i = 0; i < 4; ++i) {
            const int mbase = bm * 128 + wm * 64 + i * 16 + quad * 4;
            #pragma unroll
            for (int r = 0; r < 4; ++r) {
                const float zpre = accz[i][j][r] + bzv;
                const float hpre = acch[i][j][r] + bhv;
                const float z = 1.f / (1.f + __expf(-zpre));
                const size_t idx = (size_t)(mbase + r) * DMODEL + n;
                a_ws[idx] = 1.f - z;
                b_ws[idx] = z * hpre;
            }
        }
    }
}

// ---------------------------------------------------------------------------
// Kernel 2: per-(chunk, channel) aggregate (A = prod a, B = composed b)
// ---------------------------------------------------------------------------
__global__ __launch_bounds__(512) void scan_phase1(
    const float* __restrict__ a_ws, const float* __restrict__ b_ws,
    float* __restrict__ Aagg, float* __restrict__ Bagg)
{
    const int h = threadIdx.x;
    const int c = blockIdx.x;
    const int t0 = c * LCHUNK;
    float A = 1.f, B = 0.f;
    #pragma unroll 8
    for (int i = 0; i < LCHUNK; ++i) {
        const size_t idx = (size_t)(t0 + i) * DMODEL + h;
        const float a = a_ws[idx];
        const float b = b_ws[idx];
        A = a * A;
        B = a * B + b;
    }
    Aagg[(size_t)c * DMODEL + h] = A;
    Bagg[(size_t)c * DMODEL + h] = B;
}

// ---------------------------------------------------------------------------
// Kernel 3: per-channel Hillis-Steele scan over NCHUNK chunk aggregates.
// ---------------------------------------------------------------------------
__global__ __launch_bounds__(NCHUNK) void scan_phase2(
    const float* __restrict__ Aagg, const float* __restrict__ Bagg,
    float* __restrict__ Hpre)
{
    const int h = blockIdx.x;
    const int c = threadIdx.x;
    __shared__ float sA[NCHUNK], sB[NCHUNK];

    float A = Aagg[(size_t)c * DMODEL + h];
    float B = Bagg[(size_t)c * DMODEL + h];
    sA[c] = A; sB[c] = B;
    __syncthreads();

    for (int off = 1; off < NCHUNK; off <<= 1) {
        float pA = 1.f, pB = 0.f;
        if (c >= off) { pA = sA[c - off]; pB = sB[c - off]; }
        __syncthreads();
        const float nA = A * pA;
        const float nB = A * pB + B;
        A = nA; B = nB;
        sA[c] = A; sB[c] = B;
        __syncthreads();
    }
    const float hpre = (c == 0) ? 0.f : sB[c - 1];
    Hpre[(size_t)c * DMODEL + h] = hpre;
}

// ---------------------------------------------------------------------------
// Kernel 4: replay local recurrence from chunk prefix, write bf16 states
// ---------------------------------------------------------------------------
__global__ __launch_bounds__(512) void scan_phase3(
    const float* __restrict__ a_ws, const float* __restrict__ b_ws,
    const float* __restrict__ Hpre, bf16* __restrict__ states)
{
    const int h = threadIdx.x;
    const int c = blockIdx.x;
    const int t0 = c * LCHUNK;
    float H = Hpre[(size_t)c * DMODEL + h];
    #pragma unroll 8
    for (int i = 0; i < LCHUNK; ++i) {
        const size_t idx = (size_t)(t0 + i) * DMODEL + h;
        const float a = a_ws[idx];
        const float b = b_ws[idx];
        H = a * H + b;
        states[idx] = __float2bfloat16(H);
    }
}

// ---------------------------------------------------------------------------
// Kernel 5: out = states @ Wo^T + bo  (dtype per flag)
// ---------------------------------------------------------------------------
__global__ __launch_bounds__(256, 2) void gemm_out(
    const bf16* __restrict__ states, const bf16* __restrict__ Wo, const float* __restrict__ bo,
    void* __restrict__ out, const int* __restrict__ flag)
{
    __shared__ __bf16 As[128 * 64];
    __shared__ __bf16 Bs[128 * 64];

    const int tid  = threadIdx.x;
    const int bn   = blockIdx.x;
    const int bm   = blockIdx.y;
    const int lane = tid & 63;
    const int wave = tid >> 6;
    const int wm   = wave >> 1;
    const int wn   = wave & 1;
    const int isf32 = *flag;

    f32x4 acc[4][4];
    #pragma unroll
    for (int i = 0; i < 4; ++i)
        #pragma unroll
        for (int j = 0; j < 4; ++j)
            acc[i][j] = (f32x4){0.f, 0.f, 0.f, 0.f};

    const int row0 = tid >> 3;
    const int k8   = tid & 7;

    const bf16* ag = states + (size_t)(bm * 128) * DMODEL + k8 * 8;
    const bf16* bg = Wo     + (size_t)(bn * 128) * DMODEL + k8 * 8;

    const int quad = lane >> 4;
    const int col  = lane & 15;

    for (int k0 = 0; k0 < DMODEL; k0 += 64) {
        #pragma unroll
        for (int it = 0; it < 4; ++it) {
            const int row   = row0 + it * 32;
            const int chunk = it * 256 + tid;
            load_lds16(ag + (size_t)row * DMODEL + k0, &As[chunk * 8]);
            load_lds16(bg + (size_t)row * DMODEL + k0, &Bs[chunk * 8]);
        }
        __syncthreads();

        #pragma unroll
        for (int kk = 0; kk < 2; ++kk) {
            const int kb = kk * 32 + quad * 8;
            bf16x8 af[4], bf[4];
            #pragma unroll
            for (int i = 0; i < 4; ++i) {
                af[i] = *(const bf16x8*)&As[(wm * 64 + i * 16 + col) * 64 + kb];
                bf[i] = *(const bf16x8*)&Bs[(wn * 64 + i * 16 + col) * 64 + kb];
            }
            #pragma unroll
            for (int i = 0; i < 4; ++i)
                #pragma unroll
                for (int j = 0; j < 4; ++j)
                    acc[i][j] = __builtin_amdgcn_mfma_f32_16x16x32_bf16(af[i], bf[j], acc[i][j], 0, 0, 0);
        }
        __syncthreads();
    }

    #pragma unroll
    for (int j = 0; j < 4; ++j) {
        const int n = bn * 128 + wn * 64 + j * 16 + col;
        const float bov = bo[n];
        #pragma unroll
        for (int i = 0; i < 4; ++i) {
            const int mbase = bm * 128 + wm * 64 + i * 16 + quad * 4;
            #pragma unroll
            for (int r = 0; r < 4; ++r) {
                const float v = acc[i][j][r] + bov;
                const size_t idx = (size_t)(mbase + r) * DMODEL + n;
                if (isf32) ((float*)out)[idx] = v;
                else       ((bf16*)out)[idx]  = __float2bfloat16(v);
            }
        }
    }
}

// ---------------------------------------------------------------------------
extern "C" void kernel_launch(void* const* d_in, const int* in_sizes, int n_in,
                              void* d_out, int out_size, void* d_ws, size_t ws_size,
                              hipStream_t stream)
{
    const void* xs_r = d_in[0];
    const void* Wz_r = d_in[1];
    const void* bz_r = d_in[2];
    const void* Wh_r = d_in[3];
    const void* bh_r = d_in[4];
    const void* Wo_r = d_in[5];
    const void* bo_r = d_in[6];

    char* w = (char*)d_ws;
    bf16*  xs_c   = (bf16*) (w);                                // 16,777,216
    bf16*  Wz_c   = (bf16*) (w + 16777216ull);                  //    524,288
    bf16*  Wh_c   = (bf16*) (w + 17301504ull);                  //    524,288
    bf16*  Wo_c   = (bf16*) (w + 17825792ull);                  //    524,288
    float* bz_c   = (float*)(w + 18350080ull);                  //      2,048
    float* bh_c   = (float*)(w + 18352128ull);                  //      2,048
    float* bo_c   = (float*)(w + 18354176ull);                  //      2,048
    int*   flag   = (int*)  (w + 18356224ull);                  //        256
    float* a_ws   = (float*)(w + 18356480ull);                  // 33,554,432
    float* b_ws   = (float*)(w + 51910912ull);                  // 33,554,432
    bf16*  states = (bf16*) (w + 85465344ull);                  // 16,777,216
    float* Aagg   = (float*)(w + 102242560ull);                 //    524,288
    float* Bagg   = (float*)(w + 102766848ull);                 //    524,288
    float* Hpre   = (float*)(w + 103291136ull);                 //    524,288

    k_detect<<<1, 256, 0, stream>>>((const unsigned short*)xs_r, flag);
    k_convert_bf16<<<(XS_N + 255) / 256, 256, 0, stream>>>(xs_r, xs_c, XS_N, flag);
    k_convert_bf16<<<(W_N + 255) / 256, 256, 0, stream>>>(Wz_r, Wz_c, W_N, flag);
    k_convert_bf16<<<(W_N + 255) / 256, 256, 0, stream>>>(Wh_r, Wh_c, W_N, flag);
    k_convert_bf16<<<(W_N + 255) / 256, 256, 0, stream>>>(Wo_r, Wo_c, W_N, flag);
    k_convert_bias<<<2, 256, 0, stream>>>(bz_r, bh_r, bo_r, bz_c, bh_c, bo_c, flag);

    gemm_zh<<<dim3(4, 128), 256, 0, stream>>>(xs_c, Wz_c, bz_c, Wh_c, bh_c, a_ws, b_ws);
    scan_phase1<<<NCHUNK, 512, 0, stream>>>(a_ws, b_ws, Aagg, Bagg);
    scan_phase2<<<DMODEL, NCHUNK, 0, stream>>>(Aagg, Bagg, Hpre);
    scan_phase3<<<NCHUNK, 512, 0, stream>>>(a_ws, b_ws, Hpre, states);
    gemm_out<<<dim3(4, 128), 256, 0, stream>>>(states, Wo_c, bo_c, d_out, flag);
}

// Round 3
// 160.189 us; speedup vs baseline: 1.1774x; 1.1774x over previous
//
#include <hip/hip_runtime.h>
#include <hip/hip_bf16.h>
#include <cstdint>
#include <cmath>

// Problem constants — inputs/outputs are fp32 (verified R1 vs R2: bf16
// interpretation NaN'd, fp32-detector path passed).
#define T_SEQ 16384
#define DMODEL 512        // D_IN = D_HID = D_OUT = 512
#define NCHUNK 512        // scan chunks (2 blocks/CU in scan phases)
#define LCHUNK 32         // T_SEQ / NCHUNK
#define XS_N   (T_SEQ * DMODEL)     // 8388608
#define W_N    (DMODEL * DMODEL)    // 262144
#define N4_XS  (XS_N / 4)           // 2097152
#define N4_W   (W_N / 4)            // 65536
#define N4_TOT (N4_XS + 3 * N4_W)   // 2293760

typedef __bf16 bf16x8 __attribute__((ext_vector_type(8)));
typedef float  f32x4  __attribute__((ext_vector_type(4)));

using bf16 = __hip_bfloat16;

__device__ __forceinline__ void load_lds16(const void* g, void* l) {
    __builtin_amdgcn_global_load_lds((const __attribute__((address_space(1))) void*)g,
                                     (__attribute__((address_space(3))) void*)l,
                                     16, 0, 0);
}

// fp32 -> bf16 bits, round-to-nearest-even
__device__ __forceinline__ unsigned short f2bf(float f) {
    union { float f; unsigned u; } v; v.f = f;
    const unsigned r = (v.u + 0x7FFFu + ((v.u >> 16) & 1u)) >> 16;
    return (unsigned short)r;
}
__device__ __forceinline__ float bf2f(unsigned short u) {
    union { unsigned u; float f; } v; v.u = ((unsigned)u) << 16;
    return v.f;
}

// ---------------------------------------------------------------------------
// Kernel 0: convert xs, Wz, Wh, Wo fp32 -> bf16 (vectorized x4)
// ---------------------------------------------------------------------------
__global__ __launch_bounds__(256) void k_convert(
    const float* __restrict__ xs, const float* __restrict__ Wz,
    const float* __restrict__ Wh, const float* __restrict__ Wo,
    bf16* __restrict__ xs_c, bf16* __restrict__ Wz_c,
    bf16* __restrict__ Wh_c, bf16* __restrict__ Wo_c)
{
    const int i = blockIdx.x * 256 + threadIdx.x;
    if (i >= N4_TOT) return;
    const float* src;
    bf16* dst;
    int o;
    if (i < N4_XS) { src = xs; dst = xs_c; o = i; }
    else {
        const int j = i - N4_XS;
        const int w = j >> 16;            // which weight
        o = j & 65535;
        src = (w == 0) ? Wz : (w == 1) ? Wh : Wo;
        dst = (w == 0) ? Wz_c : (w == 1) ? Wh_c : Wo_c;
    }
    const float4 v = ((const float4*)src)[o];
    ushort4 r;
    r.x = f2bf(v.x); r.y = f2bf(v.y); r.z = f2bf(v.z); r.w = f2bf(v.w);
    ((ushort4*)dst)[o] = r;
}

// ---------------------------------------------------------------------------
// Kernel 1: fused dual GEMM  zpre = xs@Wz^T, hpre = xs@Wh^T  (NT layout)
// epilogue: z = sigmoid(zpre+bz); a = 1-z; b = z*(hpre+bh)
//           packed as bf16 pair in one u32 -> ab_ws
// ---------------------------------------------------------------------------
__global__ __launch_bounds__(256, 2) void gemm_zh(
    const bf16* __restrict__ xs, const bf16* __restrict__ Wz, const float* __restrict__ bz,
    const bf16* __restrict__ Wh, const float* __restrict__ bh,
    unsigned int* __restrict__ ab_ws)
{
    __shared__ __bf16 As[128 * 64];
    __shared__ __bf16 Zs[128 * 64];
    __shared__ __bf16 Hs[128 * 64];

    const int tid  = threadIdx.x;
    const int bn   = blockIdx.x;   // 0..3   (N tile)
    const int bm   = blockIdx.y;   // 0..127 (M tile)
    const int lane = tid & 63;
    const int wave = tid >> 6;
    const int wm   = wave >> 1;
    const int wn   = wave & 1;

    f32x4 accz[4][4], acch[4][4];
    #pragma unroll
    for (int i = 0; i < 4; ++i)
        #pragma unroll
        for (int j = 0; j < 4; ++j) {
            accz[i][j] = (f32x4){0.f, 0.f, 0.f, 0.f};
            acch[i][j] = (f32x4){0.f, 0.f, 0.f, 0.f};
        }

    const int row0 = tid >> 3;
    const int k8   = tid & 7;

    const bf16* xg = xs + (size_t)(bm * 128) * DMODEL + k8 * 8;
    const bf16* zg = Wz + (size_t)(bn * 128) * DMODEL + k8 * 8;
    const bf16* hg = Wh + (size_t)(bn * 128) * DMODEL + k8 * 8;

    const int quad = lane >> 4;
    const int col  = lane & 15;

    for (int k0 = 0; k0 < DMODEL; k0 += 64) {
        #pragma unroll
        for (int it = 0; it < 4; ++it) {
            const int row   = row0 + it * 32;
            const int chunk = it * 256 + tid;
            load_lds16(xg + (size_t)row * DMODEL + k0, &As[chunk * 8]);
            load_lds16(zg + (size_t)row * DMODEL + k0, &Zs[chunk * 8]);
            load_lds16(hg + (size_t)row * DMODEL + k0, &Hs[chunk * 8]);
        }
        __syncthreads();

        #pragma unroll
        for (int kk = 0; kk < 2; ++kk) {
            const int kb = kk * 32 + quad * 8;
            bf16x8 af[4], zf[4], hf[4];
            #pragma unroll
            for (int i = 0; i < 4; ++i) {
                const int am  = wm * 64 + i * 16 + col;
                const int bnr = wn * 64 + i * 16 + col;
                af[i] = *(const bf16x8*)&As[am * 64 + kb];
                zf[i] = *(const bf16x8*)&Zs[bnr * 64 + kb];
                hf[i] = *(const bf16x8*)&Hs[bnr * 64 + kb];
            }
            #pragma unroll
            for (int i = 0; i < 4; ++i)
                #pragma unroll
                for (int j = 0; j < 4; ++j) {
                    accz[i][j] = __builtin_amdgcn_mfma_f32_16x16x32_bf16(af[i], zf[j], accz[i][j], 0, 0, 0);
                    acch[i][j] = __builtin_amdgcn_mfma_f32_16x16x32_bf16(af[i], hf[j], acch[i][j], 0, 0, 0);
                }
        }
        __syncthreads();
    }

    // epilogue: D layout col=lane&15 (n), row=quad*4+reg (m)
    #pragma unroll
    for (int j = 0; j < 4; ++j) {
        const int n = bn * 128 + wn * 64 + j * 16 + col;
        const float bzv = bz[n];
        const float bhv = bh[n];
        #pragma unroll
        for (int i = 0; i < 4; ++i) {
            const int mbase = bm * 128 + wm * 64 + i * 16 + quad * 4;
            #pragma unroll
            for (int r = 0; r < 4; ++r) {
                const float zpre = accz[i][j][r] + bzv;
                const float hpre = acch[i][j][r] + bhv;
                const float z = 1.f / (1.f + __expf(-zpre));
                const float a = 1.f - z;
                const float b = z * hpre;
                const size_t idx = (size_t)(mbase + r) * DMODEL + n;
                ab_ws[idx] = (unsigned)f2bf(a) | ((unsigned)f2bf(b) << 16);
            }
        }
    }
}

// ---------------------------------------------------------------------------
// Kernel 2: per-(chunk, channel) aggregate (A = prod a, B = composed b)
// grid = NCHUNK blocks x 512 threads (thread = channel) -> coalesced 4B loads
// ---------------------------------------------------------------------------
__global__ __launch_bounds__(512) void scan_phase1(
    const unsigned int* __restrict__ ab_ws,
    float* __restrict__ Aagg, float* __restrict__ Bagg)
{
    const int h = threadIdx.x;
    const int c = blockIdx.x;
    const int t0 = c * LCHUNK;
    float A = 1.f, B = 0.f;
    #pragma unroll 8
    for (int i = 0; i < LCHUNK; ++i) {
        const unsigned u = ab_ws[(size_t)(t0 + i) * DMODEL + h];
        const float a = bf2f((unsigned short)(u & 0xFFFFu));
        const float b = bf2f((unsigned short)(u >> 16));
        A = a * A;
        B = a * B + b;
    }
    Aagg[(size_t)c * DMODEL + h] = A;
    Bagg[(size_t)c * DMODEL + h] = B;
}

// ---------------------------------------------------------------------------
// Kernel 3: per-channel Hillis-Steele scan over NCHUNK chunk aggregates.
// grid = 512 channel-blocks x NCHUNK threads (thread = chunk)
// ---------------------------------------------------------------------------
__global__ __launch_bounds__(NCHUNK) void scan_phase2(
    const float* __restrict__ Aagg, const float* __restrict__ Bagg,
    float* __restrict__ Hpre)
{
    const int h = blockIdx.x;
    const int c = threadIdx.x;
    __shared__ float sA[NCHUNK], sB[NCHUNK];

    float A = Aagg[(size_t)c * DMODEL + h];
    float B = Bagg[(size_t)c * DMODEL + h];
    sA[c] = A; sB[c] = B;
    __syncthreads();

    for (int off = 1; off < NCHUNK; off <<= 1) {
        float pA = 1.f, pB = 0.f;
        if (c >= off) { pA = sA[c - off]; pB = sB[c - off]; }
        __syncthreads();
        const float nA = A * pA;
        const float nB = A * pB + B;
        A = nA; B = nB;
        sA[c] = A; sB[c] = B;
        __syncthreads();
    }
    const float hpre = (c == 0) ? 0.f : sB[c - 1];
    Hpre[(size_t)c * DMODEL + h] = hpre;
}

// ---------------------------------------------------------------------------
// Kernel 4: replay local recurrence from chunk prefix, write bf16 states
// ---------------------------------------------------------------------------
__global__ __launch_bounds__(512) void scan_phase3(
    const unsigned int* __restrict__ ab_ws,
    const float* __restrict__ Hpre, bf16* __restrict__ states)
{
    const int h = threadIdx.x;
    const int c = blockIdx.x;
    const int t0 = c * LCHUNK;
    float H = Hpre[(size_t)c * DMODEL + h];
    #pragma unroll 8
    for (int i = 0; i < LCHUNK; ++i) {
        const size_t idx = (size_t)(t0 + i) * DMODEL + h;
        const unsigned u = ab_ws[idx];
        const float a = bf2f((unsigned short)(u & 0xFFFFu));
        const float b = bf2f((unsigned short)(u >> 16));
        H = a * H + b;
        ((unsigned short*)states)[idx] = f2bf(H);
    }
}

// ---------------------------------------------------------------------------
// Kernel 5: out = states @ Wo^T + bo  (fp32 out)
// ---------------------------------------------------------------------------
__global__ __launch_bounds__(256, 2) void gemm_out(
    const bf16* __restrict__ states, const bf16* __restrict__ Wo, const float* __restrict__ bo,
    float* __restrict__ out)
{
    __shared__ __bf16 As[128 * 64];
    __shared__ __bf16 Bs[128 * 64];

    const int tid  = threadIdx.x;
    const int bn   = blockIdx.x;
    const int bm   = blockIdx.y;
    const int lane = tid & 63;
    const int wave = tid >> 6;
    const int wm   = wave >> 1;
    const int wn   = wave & 1;

    f32x4 acc[4][4];
    #pragma unroll
    for (int i = 0; i < 4; ++i)
        #pragma unroll
        for (int j = 0; j < 4; ++j)
            acc[i][j] = (f32x4){0.f, 0.f, 0.f, 0.f};

    const int row0 = tid >> 3;
    const int k8   = tid & 7;

    const bf16* ag = states + (size_t)(bm * 128) * DMODEL + k8 * 8;
    const bf16* bg = Wo     + (size_t)(bn * 128) * DMODEL + k8 * 8;

    const int quad = lane >> 4;
    const int col  = lane & 15;

    for (int k0 = 0; k0 < DMODEL; k0 += 64) {
        #pragma unroll
        for (int it = 0; it < 4; ++it) {
            const int row   = row0 + it * 32;
            const int chunk = it * 256 + tid;
            load_lds16(ag + (size_t)row * DMODEL + k0, &As[chunk * 8]);
            load_lds16(bg + (size_t)row * DMODEL + k0, &Bs[chunk * 8]);
        }
        __syncthreads();

        #pragma unroll
        for (int kk = 0; kk < 2; ++kk) {
            const int kb = kk * 32 + quad * 8;
            bf16x8 af[4], bf[4];
            #pragma unroll
            for (int i = 0; i < 4; ++i) {
                af[i] = *(const bf16x8*)&As[(wm * 64 + i * 16 + col) * 64 + kb];
                bf[i] = *(const bf16x8*)&Bs[(wn * 64 + i * 16 + col) * 64 + kb];
            }
            #pragma unroll
            for (int i = 0; i < 4; ++i)
                #pragma unroll
                for (int j = 0; j < 4; ++j)
                    acc[i][j] = __builtin_amdgcn_mfma_f32_16x16x32_bf16(af[i], bf[j], acc[i][j], 0, 0, 0);
        }
        __syncthreads();
    }

    #pragma unroll
    for (int j = 0; j < 4; ++j) {
        const int n = bn * 128 + wn * 64 + j * 16 + col;
        const float bov = bo[n];
        #pragma unroll
        for (int i = 0; i < 4; ++i) {
            const int mbase = bm * 128 + wm * 64 + i * 16 + quad * 4;
            #pragma unroll
            for (int r = 0; r < 4; ++r)
                out[(size_t)(mbase + r) * DMODEL + n] = acc[i][j][r] + bov;
        }
    }
}

// ---------------------------------------------------------------------------
extern "C" void kernel_launch(void* const* d_in, const int* in_sizes, int n_in,
                              void* d_out, int out_size, void* d_ws, size_t ws_size,
                              hipStream_t stream)
{
    const float* xs = (const float*)d_in[0];
    const float* Wz = (const float*)d_in[1];
    const float* bz = (const float*)d_in[2];
    const float* Wh = (const float*)d_in[3];
    const float* bh = (const float*)d_in[4];
    const float* Wo = (const float*)d_in[5];
    const float* bo = (const float*)d_in[6];
    float* out = (float*)d_out;

    char* w = (char*)d_ws;
    bf16*  xs_c   = (bf16*) (w);                     // 16,777,216
    bf16*  Wz_c   = (bf16*) (w + 16777216ull);       //    524,288
    bf16*  Wh_c   = (bf16*) (w + 17301504ull);       //    524,288
    bf16*  Wo_c   = (bf16*) (w + 17825792ull);       //    524,288
    unsigned int* ab_ws = (unsigned int*)(w + 18350080ull);  // 33,554,432
    bf16*  states = (bf16*) (w + 51904512ull);       // 16,777,216
    float* Aagg   = (float*)(w + 68681728ull);       //  1,048,576
    float* Bagg   = (float*)(w + 69730304ull);       //  1,048,576
    float* Hpre   = (float*)(w + 70778880ull);       //  1,048,576

    k_convert<<<(N4_TOT + 255) / 256, 256, 0, stream>>>(xs, Wz, Wh, Wo, xs_c, Wz_c, Wh_c, Wo_c);
    gemm_zh<<<dim3(4, 128), 256, 0, stream>>>(xs_c, Wz_c, bz, Wh_c, bh, ab_ws);
    scan_phase1<<<NCHUNK, 512, 0, stream>>>(ab_ws, Aagg, Bagg);
    scan_phase2<<<DMODEL, NCHUNK, 0, stream>>>(Aagg, Bagg, Hpre);
    scan_phase3<<<NCHUNK, 512, 0, stream>>>(ab_ws, Hpre, states);
    gemm_out<<<dim3(4, 128), 256, 0, stream>>>(states, Wo_c, bo, out);
}